// Round 1
// baseline (155.112 us; speedup 1.0000x reference)
//
#include <hip/hip_runtime.h>
#include <math.h>

#define B_ 32
#define N_ 16384
#define D_ 128
#define NEG_SLOPE 0.2f
#define CHUNKS 16      // chunks per batch
#define ITERS 8        // 128-row tiles per chunk (1024 rows/chunk)
#define TILE_ROWS 128

typedef __attribute__((ext_vector_type(8))) short short8;
typedef __attribute__((ext_vector_type(4))) float f32x4;

__device__ __forceinline__ unsigned short f2bf(float x) {
    union { float f; unsigned int u; } v; v.f = x;
    unsigned int r = v.u + 0x7FFFu + ((v.u >> 16) & 1u);   // RNE
    return (unsigned short)(r >> 16);
}

// ---------------- kernel 1: h_query = query @ Wq^T ----------------
__global__ void hq_kernel(const float* __restrict__ query,
                          const float* __restrict__ Wq,
                          float* __restrict__ hq) {
    int b = blockIdx.x, h = threadIdx.x;           // 32 blocks x 128 threads
    const float4* q4 = (const float4*)(query + (size_t)b * D_);
    const float4* w4 = (const float4*)(Wq + (size_t)h * D_);
    float s = 0.f;
#pragma unroll
    for (int k = 0; k < D_ / 4; ++k) {
        float4 q = q4[k], w = w4[k];
        s += q.x * w.x + q.y * w.y + q.z * w.z + q.w * w.w;
    }
    hq[b * D_ + h] = s;
}

// ---------------- kernel 2: fused h_key GEMM + logits + online softmax accum ----------------
__global__ __launch_bounds__(256, 2) void
main_kernel(const float* __restrict__ key, const float* __restrict__ Wk,
            const float* __restrict__ Wa, const float* __restrict__ hq,
            float* __restrict__ logits, float* __restrict__ part) {
    __shared__ unsigned short kt[TILE_ROWS * D_];   // bf16 key tile, XOR-swizzled, 32 KB
    __shared__ float comb_acc[4][D_];
    __shared__ float comb_m[4], comb_l[4];

    const int b = blockIdx.y, chunk = blockIdx.x;
    const int tid = threadIdx.x;
    const int w = tid >> 6;            // wave 0..3
    const int lane = tid & 63;
    const int ln = lane & 15;          // row/col-within-fragment lane index
    const int g = lane >> 4;           // k-group
    const int n0 = chunk * (N_ / CHUNKS);

    // ---- Wk fragments (B operand, B[k][c] = Wk[c][k]) resident in registers ----
    short8 bfrag[8][4];
#pragma unroll
    for (int cf = 0; cf < 8; ++cf) {
        const float* wp = Wk + (size_t)(cf * 16 + ln) * D_;
#pragma unroll
        for (int kk = 0; kk < 4; ++kk) {
            const float4* p = (const float4*)(wp + kk * 32 + g * 8);
            float4 x = p[0], y = p[1];
            short8 f;
            f[0] = f2bf(x.x); f[1] = f2bf(x.y); f[2] = f2bf(x.z); f[3] = f2bf(x.w);
            f[4] = f2bf(y.x); f[5] = f2bf(y.y); f[6] = f2bf(y.z); f[7] = f2bf(y.w);
            bfrag[cf][kk] = f;
        }
    }
    float hq_r[8], wa_r[8];
#pragma unroll
    for (int cf = 0; cf < 8; ++cf) {
        hq_r[cf] = hq[b * D_ + cf * 16 + ln];
        wa_r[cf] = Wa[cf * 16 + ln];
    }

    float m_w = -1e30f, l_w = 0.f;
    float accl[8];
#pragma unroll
    for (int cf = 0; cf < 8; ++cf) accl[cf] = 0.f;

    const float* kbase = key + ((size_t)b * N_ + n0) * D_;

    for (int it = 0; it < ITERS; ++it) {
        __syncthreads();  // previous tile's readers done before overwrite
        // ---- stage 128x128 key tile: fp32 global -> bf16 swizzled LDS ----
        const float* src0 = kbase + (size_t)it * TILE_ROWS * D_;
#pragma unroll
        for (int half = 0; half < 2; ++half) {
            int r = (tid >> 2) + half * 64;
            int c = (tid & 3) * 32;
            const float4* s4 = (const float4*)(src0 + (size_t)r * D_ + c);
            int sw = (r & 7) << 3;   // XOR swizzle in ushort units (16B granules)
#pragma unroll
            for (int u = 0; u < 4; ++u) {
                float4 x = s4[2 * u], y = s4[2 * u + 1];
                short8 f;
                f[0] = f2bf(x.x); f[1] = f2bf(x.y); f[2] = f2bf(x.z); f[3] = f2bf(x.w);
                f[4] = f2bf(y.x); f[5] = f2bf(y.y); f[6] = f2bf(y.z); f[7] = f2bf(y.w);
                int idx = (r * D_ + c + u * 8) ^ sw;
                *(short8*)&kt[idx] = f;
            }
        }
        __syncthreads();

        // ---- MFMA: h_key tile rows [w*32, w*32+32) x all 128 cols ----
        f32x4 acc[2][8] = {};
#pragma unroll
        for (int kk = 0; kk < 4; ++kk) {
            int r0 = w * 32 + ln;
            int i0 = (r0 * D_ + kk * 32 + g * 8) ^ ((r0 & 7) << 3);
            short8 a0 = *(const short8*)&kt[i0];
            int r1 = r0 + 16;
            int i1 = (r1 * D_ + kk * 32 + g * 8) ^ ((r1 & 7) << 3);
            short8 a1 = *(const short8*)&kt[i1];
#pragma unroll
            for (int cf = 0; cf < 8; ++cf) {
                acc[0][cf] = __builtin_amdgcn_mfma_f32_16x16x32_bf16(a0, bfrag[cf][kk], acc[0][cf], 0, 0, 0);
                acc[1][cf] = __builtin_amdgcn_mfma_f32_16x16x32_bf16(a1, bfrag[cf][kk], acc[1][cf], 0, 0, 0);
            }
        }

        // ---- logits: lrelu(hq + h_key) . Wa, 16-lane reduce ----
        float lg[2][4];
#pragma unroll
        for (int rf = 0; rf < 2; ++rf) {
#pragma unroll
            for (int j = 0; j < 4; ++j) {
                float s = 0.f;
#pragma unroll
                for (int cf = 0; cf < 8; ++cf) {
                    float v = hq_r[cf] + acc[rf][cf][j];
                    v = (v > 0.f) ? v : (NEG_SLOPE * v);
                    s = fmaf(v, wa_r[cf], s);
                }
                s += __shfl_xor(s, 1);
                s += __shfl_xor(s, 2);
                s += __shfl_xor(s, 4);
                s += __shfl_xor(s, 8);
                lg[rf][j] = s;   // logit of row rf*16 + g*4 + j (all 16 lanes of group)
            }
        }
        int nbase = n0 + it * TILE_ROWS + w * 32;
        if (ln == 0) {
            float4 v0 = make_float4(lg[0][0], lg[0][1], lg[0][2], lg[0][3]);
            float4 v1 = make_float4(lg[1][0], lg[1][1], lg[1][2], lg[1][3]);
            *(float4*)&logits[(size_t)b * N_ + nbase + g * 4] = v0;
            *(float4*)&logits[(size_t)b * N_ + nbase + 16 + g * 4] = v1;
        }

        // ---- online softmax accumulate (per wave) ----
        float mt = lg[0][0];
#pragma unroll
        for (int rf = 0; rf < 2; ++rf)
#pragma unroll
            for (int j = 0; j < 4; ++j) mt = fmaxf(mt, lg[rf][j]);
        mt = fmaxf(mt, __shfl_xor(mt, 16));
        mt = fmaxf(mt, __shfl_xor(mt, 32));
        float m_new = fmaxf(m_w, mt);
        float corr = __expf(m_w - m_new);
        l_w *= corr;
#pragma unroll
        for (int cf = 0; cf < 8; ++cf) accl[cf] *= corr;
#pragma unroll
        for (int rf = 0; rf < 2; ++rf) {
#pragma unroll
            for (int j = 0; j < 4; ++j) {
                float p = __expf(lg[rf][j] - m_new);
                l_w += (ln == 0) ? p : 0.f;   // count each row once per group
#pragma unroll
                for (int cf = 0; cf < 8; ++cf)
                    accl[cf] = fmaf(p, acc[rf][cf][j], accl[cf]);
            }
        }
        m_w = m_new;
    }

    // ---- block combine ----
#pragma unroll
    for (int cf = 0; cf < 8; ++cf) {
        accl[cf] += __shfl_xor(accl[cf], 16);
        accl[cf] += __shfl_xor(accl[cf], 32);
    }
    l_w += __shfl_xor(l_w, 1);
    l_w += __shfl_xor(l_w, 2);
    l_w += __shfl_xor(l_w, 4);
    l_w += __shfl_xor(l_w, 8);
    l_w += __shfl_xor(l_w, 16);
    l_w += __shfl_xor(l_w, 32);
    if (lane < 16) {
#pragma unroll
        for (int cf = 0; cf < 8; ++cf)
            comb_acc[w][cf * 16 + ln] = accl[cf];
    }
    if (lane == 0) { comb_m[w] = m_w; comb_l[w] = l_w; }
    __syncthreads();
    if (tid < D_) {
        float mb = fmaxf(fmaxf(comb_m[0], comb_m[1]), fmaxf(comb_m[2], comb_m[3]));
        float lb = 0.f, ab = 0.f;
#pragma unroll
        for (int ww = 0; ww < 4; ++ww) {
            float cw = __expf(comb_m[ww] - mb);
            lb = fmaf(comb_l[ww], cw, lb);
            ab = fmaf(comb_acc[ww][tid], cw, ab);
        }
        float* pp = part + ((size_t)b * CHUNKS + chunk) * 132;
        pp[2 + tid] = ab;
        if (tid == 0) pp[0] = mb;
        if (tid == 1) pp[1] = lb;
    }
}

// ---------------- kernel 3: combine chunk partials -> h_prime, store (m_b, l_b) ----------------
__global__ void finish_kernel(const float* __restrict__ part,
                              float* __restrict__ out_hp,
                              float* __restrict__ mblb) {
    int b = blockIdx.x, h = threadIdx.x;   // 32 x 128
    float mb = -1e30f;
    for (int c = 0; c < CHUNKS; ++c)
        mb = fmaxf(mb, part[((size_t)b * CHUNKS + c) * 132]);
    float lb = 0.f, ac = 0.f;
    for (int c = 0; c < CHUNKS; ++c) {
        const float* pp = part + ((size_t)b * CHUNKS + c) * 132;
        float cw = __expf(pp[0] - mb);
        lb = fmaf(pp[1], cw, lb);
        ac = fmaf(pp[2 + h], cw, ac);
    }
    float scored = ac / lb;
    out_hp[b * D_ + h] = (scored > 0.f) ? scored : expm1f(scored);
    if (h == 0) { mblb[b * 2] = mb; mblb[b * 2 + 1] = lb; }
}

// ---------------- kernel 4: e = exp(logit - m_b) / l_b ----------------
__global__ void e_kernel(const float* __restrict__ logits,
                         const float* __restrict__ mblb,
                         float* __restrict__ out_e) {
    int idx = blockIdx.x * blockDim.x + threadIdx.x;  // 0 .. B*N/4 - 1
    int n4 = idx * 4;
    int b = n4 >> 14;   // N_ = 16384
    float mb = mblb[b * 2];
    float inv = 1.f / mblb[b * 2 + 1];
    float4 lg = *(const float4*)&logits[(size_t)n4];
    float4 e;
    e.x = __expf(lg.x - mb) * inv;
    e.y = __expf(lg.y - mb) * inv;
    e.z = __expf(lg.z - mb) * inv;
    e.w = __expf(lg.w - mb) * inv;
    *(float4*)&out_e[(size_t)n4] = e;
}

extern "C" void kernel_launch(void* const* d_in, const int* in_sizes, int n_in,
                              void* d_out, int out_size, void* d_ws, size_t ws_size,
                              hipStream_t stream) {
    const float* query = (const float*)d_in[0];
    const float* key   = (const float*)d_in[1];
    const float* Wq    = (const float*)d_in[2];
    const float* Wk    = (const float*)d_in[3];
    const float* Wa    = (const float*)d_in[4];
    float* out = (float*)d_out;

    float* ws     = (float*)d_ws;
    float* hq     = ws;                                   // 4096
    float* logits = ws + 4096;                            // B*N = 524288
    float* part   = logits + (size_t)B_ * N_;             // 32*16*132 = 67584
    float* mblb   = part + (size_t)B_ * CHUNKS * 132;     // 64

    hq_kernel<<<dim3(B_), dim3(D_), 0, stream>>>(query, Wq, hq);
    main_kernel<<<dim3(CHUNKS, B_), dim3(256), 0, stream>>>(key, Wk, Wa, hq, logits, part);
    finish_kernel<<<dim3(B_), dim3(D_), 0, stream>>>(part, out, mblb);
    e_kernel<<<dim3((B_ * N_ / 4) / 256), dim3(256), 0, stream>>>(logits, mblb, out + B_ * D_);
}

// Round 2
// 80.735 us; speedup vs baseline: 1.9212x; 1.9212x over previous
//
#include <hip/hip_runtime.h>
#include <math.h>

#define B_ 32
#define N_ 16384
#define D_ 128
#define NEG_SLOPE 0.2f
#define CHUNKS 16      // chunks per batch (grid 16x32 = 512 blocks = 2/CU exact fit)
#define TILE 64        // rows per tile
#define ITERS 16       // (N_/CHUNKS)/TILE

typedef __attribute__((ext_vector_type(8))) short short8;
typedef __attribute__((ext_vector_type(4))) float f32x4;

__device__ __forceinline__ unsigned short f2bf(float x) {
    union { float f; unsigned int u; } v; v.f = x;
    unsigned int r = v.u + 0x7FFFu + ((v.u >> 16) & 1u);   // RNE
    return (unsigned short)(r >> 16);
}

// ---------------- kernel 1: h_query = query @ Wq^T ----------------
__global__ void hq_kernel(const float* __restrict__ query,
                          const float* __restrict__ Wq,
                          float* __restrict__ hq) {
    int b = blockIdx.x, h = threadIdx.x;           // 32 blocks x 128 threads
    const float4* q4 = (const float4*)(query + (size_t)b * D_);
    const float4* w4 = (const float4*)(Wq + (size_t)h * D_);
    float s = 0.f;
#pragma unroll
    for (int k = 0; k < D_ / 4; ++k) {
        float4 q = q4[k], w = w4[k];
        s += q.x * w.x + q.y * w.y + q.z * w.z + q.w * w.w;
    }
    hq[b * D_ + h] = s;
}

// ---------------- kernel 2: fused h_key GEMM + logits + online softmax accum ----------------
// Async 2-phase: global_load_lds (fp32, dbuf) + counted vmcnt, NO per-iter barriers
// (each wave stages and reads only its own 16-row strip -> no cross-wave LDS dep).
__global__ __launch_bounds__(256, 2) void
main_kernel(const float* __restrict__ key, const float* __restrict__ Wk,
            const float* __restrict__ Wa, const float* __restrict__ hq,
            float* __restrict__ logits, float* __restrict__ part) {
    __shared__ float kbuf[2][TILE * D_];   // 2 x 32 KB fp32, XOR-swizzled via source
    __shared__ float comb_acc[4][D_];
    __shared__ float comb_m[4], comb_l[4];

    const int b = blockIdx.y, chunk = blockIdx.x;
    const int tid = threadIdx.x;
    const int w = tid >> 6;            // wave 0..3
    const int lane = tid & 63;
    const int ln = lane & 15;
    const int g = lane >> 4;
    const int n0 = chunk * (N_ / CHUNKS);

    // ---- Wk fragments (B operand, B[k][c] = Wk[c][k]) resident in registers ----
    short8 bfrag[8][4];
#pragma unroll
    for (int cf = 0; cf < 8; ++cf) {
        const float* wp = Wk + (size_t)(cf * 16 + ln) * D_;
#pragma unroll
        for (int kk = 0; kk < 4; ++kk) {
            const float4* p = (const float4*)(wp + kk * 32 + g * 8);
            float4 x = p[0], y = p[1];
            short8 f;
            f[0] = f2bf(x.x); f[1] = f2bf(x.y); f[2] = f2bf(x.z); f[3] = f2bf(x.w);
            f[4] = f2bf(y.x); f[5] = f2bf(y.y); f[6] = f2bf(y.z); f[7] = f2bf(y.w);
            bfrag[cf][kk] = f;
        }
    }
    float hq_r[8], wa_r[8];
#pragma unroll
    for (int cf = 0; cf < 8; ++cf) {
        hq_r[cf] = hq[b * D_ + cf * 16 + ln];
        wa_r[cf] = Wa[cf * 16 + ln];
    }

    float m_w = -1e30f, l_w = 0.f;
    float accl[8];
#pragma unroll
    for (int cf = 0; cf < 8; ++cf) accl[cf] = 0.f;

    const char* kbase = (const char*)(key + ((size_t)b * N_ + n0) * D_);

    // stage tile `it` into kbuf[it&1]: wave w stages its own rows [w*16, w*16+16)
    // linear LDS dest + inverse-swizzled global source (rule 21 / m201 pattern)
    auto stage = [&](int it) {
        const char* gt = kbase + (size_t)it * (TILE * D_ * 4);
        char* lb = (char*)&kbuf[it & 1][0];
#pragma unroll
        for (int k = 0; k < 8; ++k) {
            unsigned Loff = (unsigned)(w * 8192 + k * 1024 + lane * 16);
            unsigned sw = ((Loff >> 9) & 7u) << 4;   // row-XOR swizzle, 16B granules
            __builtin_amdgcn_global_load_lds(
                (const __attribute__((address_space(1))) unsigned int*)(uintptr_t)(gt + (Loff ^ sw)),
                (__attribute__((address_space(3))) unsigned int*)(uintptr_t)(lb + w * 8192 + k * 1024),
                16, 0, 0);
        }
    };

    stage(0);
    for (int it = 0; it < ITERS; ++it) {
        if (it + 1 < ITERS) {
            stage(it + 1);
            asm volatile("s_waitcnt vmcnt(8)" ::: "memory");   // tile `it` landed; next 8 in flight
        } else {
            asm volatile("s_waitcnt vmcnt(0)" ::: "memory");
        }
        const char* lb = (const char*)&kbuf[it & 1][0];
        const int r = w * 16 + ln;
        const unsigned sw = (unsigned)(r & 7) << 4;

        f32x4 acc[8] = {};
#pragma unroll
        for (int kk = 0; kk < 4; ++kk) {
            unsigned off0 = (unsigned)(r * 512 + kk * 128 + g * 32);
            float4 x = *(const float4*)(lb + (off0 ^ sw));
            float4 y = *(const float4*)(lb + ((off0 + 16) ^ sw));
            short8 a;
            a[0] = f2bf(x.x); a[1] = f2bf(x.y); a[2] = f2bf(x.z); a[3] = f2bf(x.w);
            a[4] = f2bf(y.x); a[5] = f2bf(y.y); a[6] = f2bf(y.z); a[7] = f2bf(y.w);
#pragma unroll
            for (int cf = 0; cf < 8; ++cf)
                acc[cf] = __builtin_amdgcn_mfma_f32_16x16x32_bf16(a, bfrag[cf][kk], acc[cf], 0, 0, 0);
        }

        // ---- logits: lrelu(hq + h_key) . Wa, 16-lane reduce ----
        float lg[4];
#pragma unroll
        for (int j = 0; j < 4; ++j) {
            float s = 0.f;
#pragma unroll
            for (int cf = 0; cf < 8; ++cf) {
                float v = hq_r[cf] + acc[cf][j];
                v = (v > 0.f) ? v : (NEG_SLOPE * v);
                s = fmaf(v, wa_r[cf], s);
            }
            s += __shfl_xor(s, 1);
            s += __shfl_xor(s, 2);
            s += __shfl_xor(s, 4);
            s += __shfl_xor(s, 8);
            lg[j] = s;   // logit of row g*4+j (within this wave's 16 rows)
        }
        int nbase = n0 + it * TILE + w * 16;
        if (ln == 0)
            *(float4*)&logits[(size_t)b * N_ + nbase + g * 4] =
                make_float4(lg[0], lg[1], lg[2], lg[3]);

        // ---- online softmax accumulate (per wave) ----
        float mt = fmaxf(fmaxf(lg[0], lg[1]), fmaxf(lg[2], lg[3]));
        mt = fmaxf(mt, __shfl_xor(mt, 16));
        mt = fmaxf(mt, __shfl_xor(mt, 32));
        float m_new = fmaxf(m_w, mt);
        float corr = __expf(m_w - m_new);
        l_w *= corr;
#pragma unroll
        for (int cf = 0; cf < 8; ++cf) accl[cf] *= corr;
#pragma unroll
        for (int j = 0; j < 4; ++j) {
            float p = __expf(lg[j] - m_new);
            l_w += (ln == 0) ? p : 0.f;   // count each row once per group
#pragma unroll
            for (int cf = 0; cf < 8; ++cf)
                accl[cf] = fmaf(p, acc[cf][j], accl[cf]);
        }
        m_w = m_new;
    }

    // ---- block combine (4 waves, disjoint row ranges) ----
#pragma unroll
    for (int cf = 0; cf < 8; ++cf) {
        accl[cf] += __shfl_xor(accl[cf], 16);
        accl[cf] += __shfl_xor(accl[cf], 32);
    }
    l_w += __shfl_xor(l_w, 1);
    l_w += __shfl_xor(l_w, 2);
    l_w += __shfl_xor(l_w, 4);
    l_w += __shfl_xor(l_w, 8);
    l_w += __shfl_xor(l_w, 16);
    l_w += __shfl_xor(l_w, 32);
    if (lane < 16) {
#pragma unroll
        for (int cf = 0; cf < 8; ++cf)
            comb_acc[w][cf * 16 + ln] = accl[cf];
    }
    if (lane == 0) { comb_m[w] = m_w; comb_l[w] = l_w; }
    __syncthreads();
    if (tid < D_) {
        float mb = fmaxf(fmaxf(comb_m[0], comb_m[1]), fmaxf(comb_m[2], comb_m[3]));
        float lb = 0.f, ab = 0.f;
#pragma unroll
        for (int ww = 0; ww < 4; ++ww) {
            float cw = __expf(comb_m[ww] - mb);
            lb = fmaf(comb_l[ww], cw, lb);
            ab = fmaf(comb_acc[ww][tid], cw, ab);
        }
        float* pp = part + ((size_t)b * CHUNKS + chunk) * 132;
        pp[2 + tid] = ab;
        if (tid == 0) pp[0] = mb;
        if (tid == 1) pp[1] = lb;
    }
}

// ---------------- kernel 3: combine chunk partials -> h_prime, store (m_b, l_b) ----------------
__global__ void finish_kernel(const float* __restrict__ part,
                              float* __restrict__ out_hp,
                              float* __restrict__ mblb) {
    int b = blockIdx.x, h = threadIdx.x;   // 32 x 128
    float mb = -1e30f;
    for (int c = 0; c < CHUNKS; ++c)
        mb = fmaxf(mb, part[((size_t)b * CHUNKS + c) * 132]);
    float lb = 0.f, ac = 0.f;
    for (int c = 0; c < CHUNKS; ++c) {
        const float* pp = part + ((size_t)b * CHUNKS + c) * 132;
        float cw = __expf(pp[0] - mb);
        lb = fmaf(pp[1], cw, lb);
        ac = fmaf(pp[2 + h], cw, ac);
    }
    float scored = ac / lb;
    out_hp[b * D_ + h] = (scored > 0.f) ? scored : expm1f(scored);
    if (h == 0) { mblb[b * 2] = mb; mblb[b * 2 + 1] = lb; }
}

// ---------------- kernel 4: e = exp(logit - m_b) / l_b ----------------
__global__ void e_kernel(const float* __restrict__ logits,
                         const float* __restrict__ mblb,
                         float* __restrict__ out_e) {
    int idx = blockIdx.x * blockDim.x + threadIdx.x;  // 0 .. B*N/4 - 1
    int n4 = idx * 4;
    int b = n4 >> 14;   // N_ = 16384
    float mb = mblb[b * 2];
    float inv = 1.f / mblb[b * 2 + 1];
    float4 lg = *(const float4*)&logits[(size_t)n4];
    float4 e;
    e.x = __expf(lg.x - mb) * inv;
    e.y = __expf(lg.y - mb) * inv;
    e.z = __expf(lg.z - mb) * inv;
    e.w = __expf(lg.w - mb) * inv;
    *(float4*)&out_e[(size_t)n4] = e;
}

extern "C" void kernel_launch(void* const* d_in, const int* in_sizes, int n_in,
                              void* d_out, int out_size, void* d_ws, size_t ws_size,
                              hipStream_t stream) {
    const float* query = (const float*)d_in[0];
    const float* key   = (const float*)d_in[1];
    const float* Wq    = (const float*)d_in[2];
    const float* Wk    = (const float*)d_in[3];
    const float* Wa    = (const float*)d_in[4];
    float* out = (float*)d_out;

    float* ws     = (float*)d_ws;
    float* hq     = ws;                                   // 4096
    float* logits = ws + 4096;                            // B*N = 524288
    float* part   = logits + (size_t)B_ * N_;             // 32*16*132 = 67584
    float* mblb   = part + (size_t)B_ * CHUNKS * 132;     // 64

    hq_kernel<<<dim3(B_), dim3(D_), 0, stream>>>(query, Wq, hq);
    main_kernel<<<dim3(CHUNKS, B_), dim3(256), 0, stream>>>(key, Wk, Wa, hq, logits, part);
    finish_kernel<<<dim3(B_), dim3(D_), 0, stream>>>(part, out, mblb);
    e_kernel<<<dim3((B_ * N_ / 4) / 256), dim3(256), 0, stream>>>(logits, mblb, out + B_ * D_);
}

// Round 3
// 79.620 us; speedup vs baseline: 1.9481x; 1.0140x over previous
//
#include <hip/hip_runtime.h>
#include <hip/hip_bf16.h>
#include <math.h>

#define B_ 32
#define N_ 16384
#define D_ 128
#define NEG_SLOPE 0.2f
#define CHUNKS 16                      // 512 blocks = 2/CU exact fit
#define ITERS 16                       // 64-row tiles per chunk

typedef __attribute__((ext_vector_type(8))) short short8;
typedef __attribute__((ext_vector_type(4))) float f32x4;

__device__ __forceinline__ short8 cvt8(float4 x, float4 y) {
    union { unsigned u[4]; short8 s; } r;
    union { __hip_bfloat162 b; unsigned u; } t;
    t.b = __float22bfloat162_rn(make_float2(x.x, x.y)); r.u[0] = t.u;
    t.b = __float22bfloat162_rn(make_float2(x.z, x.w)); r.u[1] = t.u;
    t.b = __float22bfloat162_rn(make_float2(y.x, y.y)); r.u[2] = t.u;
    t.b = __float22bfloat162_rn(make_float2(y.z, y.w)); r.u[3] = t.u;
    return r.s;
}

template<int HALF>
__device__ __forceinline__ void compute_half(const char* lbuf, int ln, int g, int w,
                                             const short8 (&bfrag)[8][4], f32x4 (&acc)[8]) {
    const int r = w * 16 + ln;
    const unsigned swr = (unsigned)(ln & 7) << 4;
#pragma unroll
    for (int kk2 = 0; kk2 < 2; ++kk2) {
        unsigned off0 = (unsigned)(r * 256 + kk2 * 128 + g * 32);
        float4 x = *(const float4*)(lbuf + (off0 ^ swr));
        float4 y = *(const float4*)(lbuf + ((off0 + 16) ^ swr));
        short8 a = cvt8(x, y);
#pragma unroll
        for (int cf = 0; cf < 8; ++cf)
            acc[cf] = __builtin_amdgcn_mfma_f32_16x16x32_bf16(
                a, bfrag[cf][HALF * 2 + kk2], acc[cf], 0, 0, 0);
    }
}

#define WAITV(N) asm volatile("s_waitcnt vmcnt(" #N ")" ::: "memory")

// ---- fused: hq (per-block redundant) + h_key GEMM + logits + online softmax ----
// depth-3 subtile pipeline: 4-buffer LDS ring (64x64 fp32 = 16 KB each),
// counted vmcnt (steady 13 = 12 loads + 1 logits store), no per-iter barriers
// (each wave stages/reads only its own 16-row strip).
__global__ __launch_bounds__(256, 2) void
main_kernel(const float* __restrict__ query, const float* __restrict__ key,
            const float* __restrict__ Wq, const float* __restrict__ Wk,
            const float* __restrict__ Wa,
            float* __restrict__ logits, float* __restrict__ part) {
    __shared__ float kbuf[4][64 * 64];     // 64 KB ring
    __shared__ float comb_acc[4][D_];
    __shared__ float comb_m[4], comb_l[4];

    const int b = blockIdx.y, chunk = blockIdx.x;
    const int tid = threadIdx.x;
    const int w = tid >> 6;
    const int lane = tid & 63;
    const int ln = lane & 15;
    const int g = lane >> 4;
    const int n0 = chunk * (N_ / CHUNKS);

    // ---- Wk fragments (B operand: B[k][c] = Wk[c][k]) in registers ----
    short8 bfrag[8][4];
#pragma unroll
    for (int cf = 0; cf < 8; ++cf) {
        const float* wp = Wk + (size_t)(cf * 16 + ln) * D_;
#pragma unroll
        for (int kk = 0; kk < 4; ++kk) {
            const float4* p = (const float4*)(wp + kk * 32 + g * 8);
            bfrag[cf][kk] = cvt8(p[0], p[1]);
        }
    }
    // ---- hq inline: hq[b][cf*16+ln] = dot(query[b], Wq[cf*16+ln]) ----
    float hq_r[8], wa_r[8];
    {
        const float4* qv = (const float4*)(query + (size_t)b * D_);
#pragma unroll
        for (int cf = 0; cf < 8; ++cf) {
            const float4* wv = (const float4*)(Wq + (size_t)(cf * 16 + ln) * D_ + g * 32);
            float s = 0.f;
#pragma unroll
            for (int u = 0; u < 8; ++u) {
                float4 wq = wv[u], qq = qv[g * 8 + u];
                s = fmaf(wq.x, qq.x, s); s = fmaf(wq.y, qq.y, s);
                s = fmaf(wq.z, qq.z, s); s = fmaf(wq.w, qq.w, s);
            }
            s += __shfl_xor(s, 16);
            s += __shfl_xor(s, 32);
            hq_r[cf] = s;
            wa_r[cf] = Wa[cf * 16 + ln];
        }
    }

    float m_w = -1e30f, l_w = 0.f;
    float accl[8];
#pragma unroll
    for (int cf = 0; cf < 8; ++cf) accl[cf] = 0.f;

    const char* kbase = (const char*)(key + ((size_t)b * N_ + n0) * D_);
    char* lds0 = (char*)&kbuf[0][0];

    // stage subtile s (64 rows x 64 cols fp32): linear LDS dest, inverse-swizzled
    // global source (rule 21); wave w covers rows [w*16, w*16+16).
    auto stage = [&](int s) {
        const int itt = s >> 1, half = s & 1;
        const char* gt = kbase + (size_t)itt * (64 * 512) + half * 256;
        char* lb = lds0 + (s & 3) * 16384 + w * 4096;
        const int rr = lane >> 4;                       // 0..3
        const unsigned cb = (unsigned)(lane & 15) * 16;
#pragma unroll
        for (int k = 0; k < 4; ++k) {
            int rowk = k * 4 + rr;                      // 0..15 in strip; (w*16)&7==0
            unsigned src = (unsigned)((w * 16 + rowk) * 512) +
                           (cb ^ (((unsigned)(rowk & 7)) << 4));
            __builtin_amdgcn_global_load_lds(
                (const __attribute__((address_space(1))) unsigned int*)(uintptr_t)(gt + src),
                (__attribute__((address_space(3))) unsigned int*)(uintptr_t)(lb + k * 1024),
                16, 0, 0);
        }
    };

    stage(0); stage(1); stage(2);

    for (int it = 0; it < ITERS; ++it) {
        f32x4 acc[8] = {};
        {   // subtile 2it (half 0)
            int s = 2 * it;
            if (s + 3 < 32) stage(s + 3);
            if (it == 0)      WAITV(12);
            else if (it < 15) WAITV(13);
            else              WAITV(6);
            compute_half<0>(lds0 + (s & 3) * 16384, ln, g, w, bfrag, acc);
        }
        {   // subtile 2it+1 (half 1)
            int s = 2 * it + 1;
            if (s + 3 < 32) stage(s + 3);
            if (it == 0)       WAITV(12);
            else if (it < 14)  WAITV(13);
            else if (it == 14) WAITV(9);
            else               WAITV(1);
            compute_half<1>(lds0 + (s & 3) * 16384, ln, g, w, bfrag, acc);
        }

        // ---- logits: lrelu(hq + h_key) . Wa, 16-lane reduce ----
        float lg[4];
#pragma unroll
        for (int j = 0; j < 4; ++j) {
            float s = 0.f;
#pragma unroll
            for (int cf = 0; cf < 8; ++cf) {
                float v = hq_r[cf] + acc[cf][j];
                v = (v > 0.f) ? v : (NEG_SLOPE * v);
                s = fmaf(v, wa_r[cf], s);
            }
            s += __shfl_xor(s, 1);
            s += __shfl_xor(s, 2);
            s += __shfl_xor(s, 4);
            s += __shfl_xor(s, 8);
            lg[j] = s;
        }
        int nbase = n0 + it * 64 + w * 16;
        if (ln == 0)
            *(float4*)&logits[(size_t)b * N_ + nbase + g * 4] =
                make_float4(lg[0], lg[1], lg[2], lg[3]);

        // ---- online softmax accumulate (per wave) ----
        float mt = fmaxf(fmaxf(lg[0], lg[1]), fmaxf(lg[2], lg[3]));
        mt = fmaxf(mt, __shfl_xor(mt, 16));
        mt = fmaxf(mt, __shfl_xor(mt, 32));
        float m_new = fmaxf(m_w, mt);
        float corr = __expf(m_w - m_new);
        l_w *= corr;
#pragma unroll
        for (int cf = 0; cf < 8; ++cf) accl[cf] *= corr;
#pragma unroll
        for (int j = 0; j < 4; ++j) {
            float p = __expf(lg[j] - m_new);
            l_w += (ln == 0) ? p : 0.f;
#pragma unroll
            for (int cf = 0; cf < 8; ++cf)
                accl[cf] = fmaf(p, acc[cf][j], accl[cf]);
        }
        m_w = m_new;
    }

    // ---- block combine (4 waves, disjoint row ranges) ----
#pragma unroll
    for (int cf = 0; cf < 8; ++cf) {
        accl[cf] += __shfl_xor(accl[cf], 16);
        accl[cf] += __shfl_xor(accl[cf], 32);
    }
    l_w += __shfl_xor(l_w, 1);
    l_w += __shfl_xor(l_w, 2);
    l_w += __shfl_xor(l_w, 4);
    l_w += __shfl_xor(l_w, 8);
    l_w += __shfl_xor(l_w, 16);
    l_w += __shfl_xor(l_w, 32);
    if (lane < 16) {
#pragma unroll
        for (int cf = 0; cf < 8; ++cf)
            comb_acc[w][cf * 16 + ln] = accl[cf];
    }
    if (lane == 0) { comb_m[w] = m_w; comb_l[w] = l_w; }
    __syncthreads();
    if (tid < D_) {
        float mb = fmaxf(fmaxf(comb_m[0], comb_m[1]), fmaxf(comb_m[2], comb_m[3]));
        float lb = 0.f, ab = 0.f;
#pragma unroll
        for (int ww = 0; ww < 4; ++ww) {
            float cw = __expf(comb_m[ww] - mb);
            lb = fmaf(comb_l[ww], cw, lb);
            ab = fmaf(comb_acc[ww][tid], cw, ab);
        }
        float* pp = part + ((size_t)b * CHUNKS + chunk) * 132;
        pp[2 + tid] = ab;
        if (tid == 0) pp[0] = mb;
        if (tid == 1) pp[1] = lb;
    }
}

// ---- fused finish + e: per-b combine (redundant per block) + h_prime + e slice ----
__global__ __launch_bounds__(256) void
finish_e_kernel(const float* __restrict__ part, const float* __restrict__ logits,
                float* __restrict__ out) {
    const int b = blockIdx.y, s = blockIdx.x, t = threadIdx.x;
    float mb = -1e30f;
#pragma unroll
    for (int c = 0; c < CHUNKS; ++c)
        mb = fmaxf(mb, part[((size_t)b * CHUNKS + c) * 132]);
    float lb = 0.f;
#pragma unroll
    for (int c = 0; c < CHUNKS; ++c) {
        const float* pp = part + ((size_t)b * CHUNKS + c) * 132;
        lb = fmaf(pp[1], __expf(pp[0] - mb), lb);
    }
    if (s == 0 && t < D_) {
        float ac = 0.f;
#pragma unroll
        for (int c = 0; c < CHUNKS; ++c) {
            const float* pp = part + ((size_t)b * CHUNKS + c) * 132;
            ac = fmaf(pp[2 + t], __expf(pp[0] - mb), ac);
        }
        float sc = ac / lb;
        out[b * D_ + t] = (sc > 0.f) ? sc : expm1f(sc);
    }
    float inv = 1.f / lb;
    int n4 = s * 1024 + t * 4;
    float4 lg = *(const float4*)&logits[(size_t)b * N_ + n4];
    float4 e;
    e.x = __expf(lg.x - mb) * inv;
    e.y = __expf(lg.y - mb) * inv;
    e.z = __expf(lg.z - mb) * inv;
    e.w = __expf(lg.w - mb) * inv;
    *(float4*)&out[(size_t)B_ * D_ + (size_t)b * N_ + n4] = e;
}

extern "C" void kernel_launch(void* const* d_in, const int* in_sizes, int n_in,
                              void* d_out, int out_size, void* d_ws, size_t ws_size,
                              hipStream_t stream) {
    const float* query = (const float*)d_in[0];
    const float* key   = (const float*)d_in[1];
    const float* Wq    = (const float*)d_in[2];
    const float* Wk    = (const float*)d_in[3];
    const float* Wa    = (const float*)d_in[4];
    float* out = (float*)d_out;

    float* ws     = (float*)d_ws;
    float* logits = ws;                                   // B*N = 524288
    float* part   = logits + (size_t)B_ * N_;             // 32*16*132 = 67584

    main_kernel<<<dim3(CHUNKS, B_), dim3(256), 0, stream>>>(query, key, Wq, Wk, Wa, logits, part);
    finish_e_kernel<<<dim3(16, B_), dim3(256), 0, stream>>>(part, logits, out);
}